// Round 13
// baseline (1279.086 us; speedup 1.0000x reference)
//
#include <hip/hip_runtime.h>

typedef _Float16 f16;
typedef f16 f16x2 __attribute__((ext_vector_type(2)));
typedef f16 f16x4 __attribute__((ext_vector_type(4)));
typedef f16 f16x8 __attribute__((ext_vector_type(8)));
typedef float f32x4 __attribute__((ext_vector_type(4)));
typedef const void __attribute__((address_space(1)))* gas1;
typedef void __attribute__((address_space(3)))* las3;

#define NB 4096
#define NN 21
#define MROWS (NB*NN)      // 86016
#define CIN 512

// ---------------- adjacency ----------------
__global__ void k_adj(const float* __restrict__ nv1, const float* __restrict__ nv2,
                      float* __restrict__ Aout) {
  __shared__ float at[21][21];
  __shared__ float dinv[21];
  int t = threadIdx.x;
  if (t < 441) {
    int i = t / 21, j = t % 21;
    float s = 0.f;
    #pragma unroll
    for (int r = 0; r < 10; r++) s += nv1[i*10 + r] * nv2[r*21 + j];
    float v = 1.f / (1.f + expf(-s));
    if (i == j) v += 1.f;
    at[i][j] = v;
  }
  __syncthreads();
  if (t < 21) {
    float d = 0.f;
    #pragma unroll
    for (int j = 0; j < 21; j++) d += at[t][j];
    dinv[t] = d > 0.f ? rsqrtf(d) : 0.f;
  }
  __syncthreads();
  if (t < 441) {
    int i = t / 21, j = t % 21;
    float a = dinv[i] * at[i][j] * dinv[j];
    Aout[t] = a > 0.1f ? a : 0.f;
  }
}

// ------- batched transpose: all 5 weight matrices in one launch -------
// slot layout (flat block id): [0,512) W1, [512,1024) rs1w, [1024,2048) W2,
// [2048,2560) W3, [2560,3072) fcw. Each tile 32x32, block (32,8).
__global__ void k_transpose_all(const float* __restrict__ s0, const float* __restrict__ s1,
                                const float* __restrict__ s2, const float* __restrict__ s3,
                                const float* __restrict__ s4,
                                f16* __restrict__ d0, f16* __restrict__ d1,
                                f16* __restrict__ d2, f16* __restrict__ d3,
                                f16* __restrict__ d4) {
  __shared__ float tile[32][33];
  int b = blockIdx.x;
  const float* src; f16* dst; int K, N, local;
  if (b < 512)       { src = s0; dst = d0; K = 512;  N = 1024; local = b; }
  else if (b < 1024) { src = s1; dst = d1; K = 512;  N = 1024; local = b - 512; }
  else if (b < 2048) { src = s2; dst = d2; K = 1024; N = 1024; local = b - 1024; }
  else if (b < 2560) { src = s3; dst = d3; K = 1024; N = 512;  local = b - 2048; }
  else               { src = s4; dst = d4; K = 512;  N = 1024; local = b - 2560; }
  int ntn = N >> 5;
  int n0 = (local % ntn) * 32, k0 = (local / ntn) * 32;
  int tx = threadIdx.x, ty = threadIdx.y;
  #pragma unroll
  for (int i = 0; i < 4; i++)
    tile[ty + 8*i][tx] = src[(size_t)(k0 + ty + 8*i) * N + n0 + tx];
  __syncthreads();
  #pragma unroll
  for (int i = 0; i < 4; i++)
    dst[(size_t)(n0 + ty + 8*i) * K + k0 + tx] = (f16)tile[tx][ty + 8*i];
}

// ------- fused SE path: mean -> se1 -> se2 -> gate, 8 graphs per block -------
// Replaces k_mean + k_se1 + k_se2 + k_gate (2 full HBM passes over x + 2GB of
// w1/w2 L2 rebroadcast). 8-graph blocking: w1/w2 L2 traffic /8; x read once
// from HBM (gate re-read is L3-hot). LDS 36KB -> 4 blocks/CU.
__global__ __launch_bounds__(256)
void k_segate(const float* __restrict__ x, const float* __restrict__ w1,
              const float* __restrict__ w2, f16* __restrict__ xg) {
  __shared__ float xm[8][512];
  __shared__ float y1[8][128];
  __shared__ float yv[8][512];
  const int tid = threadIdx.x;
  const int g0 = blockIdx.x * 8;
  const int c0 = tid * 2;
  // node mean per graph (thread owns 2 channels)
  for (int i = 0; i < 8; i++) {
    const float* xb = x + ((size_t)(g0 + i) * NN) * 512 + c0;
    float s0 = 0.f, s1 = 0.f;
    #pragma unroll
    for (int n = 0; n < NN; n++) {
      float2 v = *(const float2*)(xb + (size_t)n * 512);
      s0 += v.x; s1 += v.y;
    }
    xm[i][c0]   = s0 * (1.f/21.f);
    xm[i][c0+1] = s1 * (1.f/21.f);
  }
  __syncthreads();
  // se1: relu(xm @ w1), outputs 8 graphs x 128; thread (o=tid&127, ih=tid>>7)
  {
    int o = tid & 127, ih = tid >> 7;
    float a0 = 0.f, a1 = 0.f, a2 = 0.f, a3 = 0.f;
    for (int k = 0; k < 512; k++) {
      float w = w1[k*128 + o];
      a0 = fmaf(xm[ih  ][k], w, a0);
      a1 = fmaf(xm[ih+2][k], w, a1);
      a2 = fmaf(xm[ih+4][k], w, a2);
      a3 = fmaf(xm[ih+6][k], w, a3);
    }
    y1[ih  ][o] = fmaxf(a0, 0.f);
    y1[ih+2][o] = fmaxf(a1, 0.f);
    y1[ih+4][o] = fmaxf(a2, 0.f);
    y1[ih+6][o] = fmaxf(a3, 0.f);
  }
  __syncthreads();
  // se2: sigmoid(y1 @ w2); thread owns channels tid and tid+256, all 8 graphs
  {
    float acc[8][2];
    #pragma unroll
    for (int i = 0; i < 8; i++) { acc[i][0] = 0.f; acc[i][1] = 0.f; }
    for (int j = 0; j < 128; j++) {
      float wa = w2[j*512 + tid];
      float wb = w2[j*512 + tid + 256];
      #pragma unroll
      for (int i = 0; i < 8; i++) {
        float yj = y1[i][j];
        acc[i][0] = fmaf(yj, wa, acc[i][0]);
        acc[i][1] = fmaf(yj, wb, acc[i][1]);
      }
    }
    #pragma unroll
    for (int i = 0; i < 8; i++) {
      yv[i][tid]       = 1.f / (1.f + expf(-acc[i][0]));
      yv[i][tid + 256] = 1.f / (1.f + expf(-acc[i][1]));
    }
  }
  __syncthreads();
  // gate: xg = f16(x * yv[graph])  (x re-read is L3-hot)
  for (int i = 0; i < 8; i++) {
    float ga = yv[i][c0], gb = yv[i][c0+1];
    size_t base = ((size_t)(g0 + i) * NN) * 512 + c0;
    #pragma unroll
    for (int n = 0; n < NN; n++) {
      float2 v = *(const float2*)(x + base + (size_t)n * 512);
      f16x2 o2; o2[0] = (f16)(v.x * ga); o2[1] = (f16)(v.y * gb);
      *(f16x2*)(xg + base + (size_t)n * 512) = o2;
    }
  }
}

// ======== 256x256 8-wave GEMM (r10 schedule — best measured) ========
// BK=64, dbuf 2x64KB LDS, 8 waves (2Mx4N), per-wave 128x64 out (acc[8][4]).
// Staging split into 4 half-stages interleaved with the 2 MFMA clusters;
// vmcnt(0)+1 barrier per K-tile. MFMA operands swapped (mfma(bv,av)) -> 4
// consecutive C-cols per acc reg -> vectorized f16x4/float4 stores.
// T2 granule-XOR swizzle on global source + ds_read (LDS dest linear).
// r11 (counted vmcnt in serial slot) and r12 (4-phase sched_barrier
// interleave) both measured == or worse; this is the plateau schedule.
// MODE 0: f16 out. MODE 1: f16 out + fused BN column-stat partials per m-block.
// MODE 2: f32 out + bias.
#define QBUF 65536

template<int MODE>
__global__ __launch_bounds__(512, 1)
void k_gemm256(const f16* __restrict__ A, const f16* __restrict__ BT,
               f16* __restrict__ C1, const float* __restrict__ bias,
               float* __restrict__ Cf, float* __restrict__ psum,
               float* __restrict__ psq, int N, int K, int lgn) {
  __shared__ __align__(16) char lds[2 * QBUF];
  const int tid = threadIdx.x;
  const int nwg = gridDim.x;
  const int g = blockIdx.x;
  const int swz = (g & 7) * (nwg >> 3) + (g >> 3);   // XCD-chunked, nwg%8==0
  const int bn = swz & ((1 << lgn) - 1);             // N fastest: A-panel L2 reuse
  const int bm = swz >> lgn;
  const int lane = tid & 63;
  const int wid = tid >> 6;
  const int wr = wid >> 2;          // 0..1 : 128-row half
  const int wc = wid & 3;           // 0..3 : 64-col slab
  const int fr = lane & 15;
  const int kg = lane >> 4;         // 0..3

  // staging: 8 granule-sets/thread/K-tile; gid=j*512+tid; j<4 -> A, else B.
  // LDS dest = gid*16 (linear); source granule pre-swizzled gr^(row&7).
  int srcOff[8];
  #pragma unroll
  for (int j = 0; j < 8; j++) {
    int gid = j * 512 + tid;
    int row = (gid >> 3) & 255;
    int gr = gid & 7;
    int gsw = gr ^ (row & 7);
    srcOff[j] = ((j < 4 ? bm : bn) * 256 + row) * K + gsw * 8;
  }
  const int ldsBase = tid * 16;     // + j*8192

  const int x7 = fr & 7;                       // swizzle key (row&7 == fr&7)
  const int aBase = (wr*128 + fr) * 128;       // + m*2048
  const int bBase = 32768 + (wc*64 + fr) * 128;// + n*2048

  f32x4 acc[8][4];
  #pragma unroll
  for (int m = 0; m < 8; m++)
    #pragma unroll
    for (int n = 0; n < 4; n++)
      #pragma unroll
      for (int r = 0; r < 4; r++) acc[m][n][r] = 0.f;

  auto STAGEH = [&](int t2, int sbuf, int j0) {   // 2 wave-loads = 16 KB
    char* dst = (char*)lds + sbuf * QBUF;
    const size_t kof = (size_t)t2 * 64;
    #pragma unroll
    for (int j = j0; j < j0 + 2; j++) {
      const f16* src = (j < 4 ? A : BT) + srcOff[j] + kof;
      __builtin_amdgcn_global_load_lds((gas1)src, (las3)(dst + ldsBase + j*8192), 16, 0, 0);
    }
  };
  auto READF = [&](f16x8* av, f16x8* bv, const char* rb, int s) {
    const int ko = ((s*4 + kg) ^ x7) << 4;
    #pragma unroll
    for (int m = 0; m < 8; m++) av[m] = *(const f16x8*)(rb + aBase + m*2048 + ko);
    #pragma unroll
    for (int n = 0; n < 4; n++) bv[n] = *(const f16x8*)(rb + bBase + n*2048 + ko);
  };

  f16x8 av[8], bv[4];
  const int NT = K >> 6;
  STAGEH(0, 0, 0); STAGEH(0, 0, 2); STAGEH(0, 0, 4); STAGEH(0, 0, 6);
  asm volatile("s_waitcnt vmcnt(0)" ::: "memory");
  asm volatile("s_barrier" ::: "memory");

  for (int t = 0; t < NT; t++) {
    const char* rb = (const char*)lds + (t & 1) * QBUF;
    const int nb = (t + 1) & 1;
    const bool stg = (t + 1) < NT;

    if (stg) { STAGEH(t + 1, nb, 0); STAGEH(t + 1, nb, 2); }   // A-tile
    READF(av, bv, rb, 0);
    __builtin_amdgcn_s_setprio(1);
    #pragma unroll
    for (int m = 0; m < 8; m++)
      #pragma unroll
      for (int n = 0; n < 4; n++)
        acc[m][n] = __builtin_amdgcn_mfma_f32_16x16x32_f16(bv[n], av[m], acc[m][n], 0, 0, 0);
    __builtin_amdgcn_s_setprio(0);
    if (stg) { STAGEH(t + 1, nb, 4); STAGEH(t + 1, nb, 6); }   // B-tile
    READF(av, bv, rb, 1);
    __builtin_amdgcn_s_setprio(1);
    #pragma unroll
    for (int m = 0; m < 8; m++)
      #pragma unroll
      for (int n = 0; n < 4; n++)
        acc[m][n] = __builtin_amdgcn_mfma_f32_16x16x32_f16(bv[n], av[m], acc[m][n], 0, 0, 0);
    __builtin_amdgcn_s_setprio(0);
    if (stg) asm volatile("s_waitcnt vmcnt(0)" ::: "memory");
    asm volatile("s_barrier" ::: "memory");   // tile t+1 resident; buf[t&1] reads retired
  }

  // swapped-operand C layout: C[bm*256 + wr*128 + m*16 + fr]
  //                            [bn*256 + wc*64 + n*16 + kg*4 + r]
  const int crow = bm*256 + wr*128 + fr;    // + m*16
  const int ccol = bn*256 + wc*64 + kg*4;   // + n*16, r contiguous
  if constexpr (MODE == 2) {
    #pragma unroll
    for (int n = 0; n < 4; n++) {
      float4 bb = *(const float4*)(bias + ccol + n*16);
      #pragma unroll
      for (int m = 0; m < 8; m++) {
        float4 v;
        v.x = acc[m][n][0] + bb.x; v.y = acc[m][n][1] + bb.y;
        v.z = acc[m][n][2] + bb.z; v.w = acc[m][n][3] + bb.w;
        *(float4*)(Cf + (size_t)(crow + m*16) * N + ccol + n*16) = v;
      }
    }
  } else {
    #pragma unroll
    for (int m = 0; m < 8; m++)
      #pragma unroll
      for (int n = 0; n < 4; n++) {
        f16x4 o;
        o[0] = (f16)acc[m][n][0]; o[1] = (f16)acc[m][n][1];
        o[2] = (f16)acc[m][n][2]; o[3] = (f16)acc[m][n][3];
        *(f16x4*)(C1 + (size_t)(crow + m*16) * N + ccol + n*16) = o;
      }
  }
  if constexpr (MODE == 1) {
    // column-stat partials over this block's 256 rows.
    float s[4][4], q[4][4];
    #pragma unroll
    for (int n = 0; n < 4; n++)
      #pragma unroll
      for (int r = 0; r < 4; r++) {
        float ss = 0.f, qq = 0.f;
        #pragma unroll
        for (int m = 0; m < 8; m++) { float v = acc[m][n][r]; ss += v; qq = fmaf(v, v, qq); }
        s[n][r] = ss; q[n][r] = qq;
      }
    #pragma unroll
    for (int n = 0; n < 4; n++)
      #pragma unroll
      for (int r = 0; r < 4; r++) {
        s[n][r] += __shfl_xor(s[n][r], 1); s[n][r] += __shfl_xor(s[n][r], 2);
        s[n][r] += __shfl_xor(s[n][r], 4); s[n][r] += __shfl_xor(s[n][r], 8);
        q[n][r] += __shfl_xor(q[n][r], 1); q[n][r] += __shfl_xor(q[n][r], 2);
        q[n][r] += __shfl_xor(q[n][r], 4); q[n][r] += __shfl_xor(q[n][r], 8);
      }
    float* wred = (float*)lds;   // [sum: [wr][256]] [sq: [wr][256]] = 4 KB
    __syncthreads();
    if (fr == 0) {
      #pragma unroll
      for (int n = 0; n < 4; n++)
        #pragma unroll
        for (int r = 0; r < 4; r++) {
          int c = wc*64 + n*16 + kg*4 + r;
          wred[wr*256 + c]       = s[n][r];
          wred[512 + wr*256 + c] = q[n][r];
        }
    }
    __syncthreads();
    if (tid < 256) {
      psum[(size_t)bm * N + bn*256 + tid] = wred[tid]       + wred[256 + tid];
      psq [(size_t)bm * N + bn*256 + tid] = wred[512 + tid] + wred[768 + tid];
    }
  }
}

// ---------------- in-place mix on [M][512] (xg -> mix(xg)) ----------------
__global__ __launch_bounds__(256)
void k_mixip(f16* __restrict__ t, const float* __restrict__ Aadj) {
  __shared__ float A[441];
  int b = blockIdx.x, tid = threadIdx.x;
  for (int i = tid; i < 441; i += 256) A[i] = Aadj[i];
  __syncthreads();
  int c0 = tid * 2;
  size_t base = (size_t)b * NN * 512 + c0;
  float vx[21], vy[21];
  #pragma unroll
  for (int j = 0; j < 21; j++) {
    f16x2 v = *(const f16x2*)(t + base + (size_t)j * 512);
    vx[j] = (float)v[0]; vy[j] = (float)v[1];
  }
  #pragma unroll
  for (int i = 0; i < 21; i++) {
    float a0 = 0.f, a1 = 0.f;
    #pragma unroll
    for (int j = 0; j < 21; j++) { float w = A[i*21+j]; a0 = fmaf(w, vx[j], a0); a1 = fmaf(w, vy[j], a1); }
    f16x2 o; o[0] = (f16)a0; o[1] = (f16)a1;
    *(f16x2*)(t + base + (size_t)i * 512) = o;
  }
}

// ------- per-graph 21x21 mix, in-place + per-graph BN stats -------
__global__ __launch_bounds__(256)
void k_mix(f16* __restrict__ t, const float* __restrict__ Aadj,
           float* __restrict__ psum, float* __restrict__ psq, int C) {
  __shared__ float A[441];
  int b = blockIdx.x, tid = threadIdx.x;
  for (int i = tid; i < 441; i += 256) A[i] = Aadj[i];
  __syncthreads();
  int c0 = (blockIdx.y * 256 + tid) * 2;
  size_t base = (size_t)b * NN * C + c0;
  float vx[21], vy[21];
  #pragma unroll
  for (int j = 0; j < 21; j++) {
    f16x2 v = *(const f16x2*)(t + base + (size_t)j * C);
    vx[j] = (float)v[0]; vy[j] = (float)v[1];
  }
  float s0 = 0.f, s1 = 0.f, q0 = 0.f, q1 = 0.f;
  #pragma unroll
  for (int i = 0; i < 21; i++) {
    float a0 = 0.f, a1 = 0.f;
    #pragma unroll
    for (int j = 0; j < 21; j++) {
      float w = A[i*21 + j];
      a0 = fmaf(w, vx[j], a0);
      a1 = fmaf(w, vy[j], a1);
    }
    f16x2 o; o[0] = (f16)a0; o[1] = (f16)a1;
    *(f16x2*)(t + base + (size_t)i * C) = o;
    s0 += a0; s1 += a1;
    q0 = fmaf(a0, a0, q0); q1 = fmaf(a1, a1, q1);
  }
  float2 sv; sv.x = s0; sv.y = s1;
  float2 qv; qv.x = q0; qv.y = q1;
  *(float2*)(psum + (size_t)b * C + c0) = sv;
  *(float2*)(psq  + (size_t)b * C + c0) = qv;
}

// ---------------- reduce partials -> groups (deterministic) --------------
__global__ void k_reduce(const float* __restrict__ ps, const float* __restrict__ pq,
                         float* __restrict__ rs, float* __restrict__ rq,
                         int C, int per) {
  int c = blockIdx.x * 256 + threadIdx.x;
  int py = blockIdx.y;
  float s = 0.f, q = 0.f;
  for (int p = py*per; p < py*per + per; p++) {
    s += ps[(size_t)p*C + c];
    q += pq[(size_t)p*C + c];
  }
  rs[(size_t)py*C + c] = s;
  rq[(size_t)py*C + c] = q;
}

// ---------------- fused partial-sum + BN params (one launch) ----------------
__global__ void k_bnfuse(const float* __restrict__ psum, const float* __restrict__ psq,
                         const float* __restrict__ gamma, const float* __restrict__ beta,
                         const float* __restrict__ resbias,
                         float* __restrict__ scale, float* __restrict__ shift,
                         int C, int npart) {
  int c = blockIdx.x * 256 + threadIdx.x;
  float s = 0.f, q = 0.f;
  for (int p = 0; p < npart; p++) { s += psum[(size_t)p*C + c]; q += psq[(size_t)p*C + c]; }
  const float Minv = 1.f / (float)MROWS;
  float mean = s * Minv;
  float var = q * Minv - mean * mean;
  float sc = gamma[c] * rsqrtf(var + 1e-5f);
  float sh = beta[c] - mean * sc;
  if (resbias) sh += resbias[c];
  scale[c] = sc; shift[c] = sh;
}

// ---------------- finalize: dst = relu(g*scale + shift + res) ----------------
__global__ void k_finalize(const f16* __restrict__ g, const f16* res,
                           f16* dst, const float* __restrict__ scale,
                           const float* __restrict__ shift, int cmask) {
  size_t i8 = (size_t)blockIdx.x * 256 + threadIdx.x;
  size_t base = i8 * 8;
  int c = (int)(base & (size_t)cmask);
  f16x8 gv = *(const f16x8*)(g + base);
  f16x8 rv = *(const f16x8*)(res + base);
  f16x8 o;
  #pragma unroll
  for (int j = 0; j < 8; j++) {
    float v = (float)gv[j] * scale[c + j] + shift[c + j] + (float)rv[j];
    o[j] = (f16)fmaxf(v, 0.f);
  }
  *(f16x8*)(dst + base) = o;
}

// ---------------- fused finish + mix: hmix = mix(relu(t*sc+sh+res)) ---------
__global__ __launch_bounds__(256)
void k_finmix(const f16* t, const f16* res, f16* hout, f16* hmix,
              const float* __restrict__ scale, const float* __restrict__ shift,
              const float* __restrict__ Aadj, int C) {
  __shared__ float A[441];
  int b = blockIdx.x, tid = threadIdx.x;
  for (int i = tid; i < 441; i += 256) A[i] = Aadj[i];
  __syncthreads();
  int c0 = (blockIdx.y * 256 + tid) * 2;
  float scx = scale[c0], scy = scale[c0+1];
  float shx = shift[c0], shy = shift[c0+1];
  size_t base = (size_t)b * NN * C + c0;
  float hx[21], hy[21];
  #pragma unroll
  for (int j = 0; j < 21; j++) {
    f16x2 tv = *(const f16x2*)(t + base + (size_t)j*C);
    f16x2 rv = *(const f16x2*)(res + base + (size_t)j*C);
    hx[j] = fmaxf((float)tv[0]*scx + shx + (float)rv[0], 0.f);
    hy[j] = fmaxf((float)tv[1]*scy + shy + (float)rv[1], 0.f);
    if (hout) {
      f16x2 o; o[0] = (f16)hx[j]; o[1] = (f16)hy[j];
      *(f16x2*)(hout + base + (size_t)j*C) = o;
    }
  }
  #pragma unroll
  for (int i = 0; i < 21; i++) {
    float a0 = 0.f, a1 = 0.f;
    #pragma unroll
    for (int j = 0; j < 21; j++) { float w = A[i*21+j]; a0 = fmaf(w, hx[j], a0); a1 = fmaf(w, hy[j], a1); }
    f16x2 o; o[0] = (f16)a0; o[1] = (f16)a1;
    *(f16x2*)(hmix + base + (size_t)i*C) = o;
  }
}

// ---------------- pool (mean over 21) + BN affine -> f16 ----------------
__global__ void k_pool(const f16* __restrict__ g3, const float* __restrict__ scale,
                       const float* __restrict__ shift, f16* __restrict__ pooled) {
  int b = blockIdx.x, t = threadIdx.x;
  for (int c = t; c < 512; c += 256) {
    float s = 0.f;
    #pragma unroll
    for (int n = 0; n < NN; n++) s += (float)g3[((size_t)b*NN + n)*512 + c];
    pooled[(size_t)b*512 + c] = (f16)((s * (1.f/21.f)) * scale[c] + shift[c]);
  }
}

extern "C" void kernel_launch(void* const* d_in, const int* in_sizes, int n_in,
                              void* d_out, int out_size, void* d_ws, size_t ws_size,
                              hipStream_t stream) {
  const float* x     = (const float*)d_in[0];
  const float* nv1   = (const float*)d_in[2];
  const float* nv2   = (const float*)d_in[3];
  const float* se_w1 = (const float*)d_in[4];
  const float* se_w2 = (const float*)d_in[5];
  const float* W1    = (const float*)d_in[6];
  const float* W2    = (const float*)d_in[8];
  const float* W3    = (const float*)d_in[10];
  const float* bn1g  = (const float*)d_in[12];
  const float* bn1b  = (const float*)d_in[13];
  const float* bn2g  = (const float*)d_in[14];
  const float* bn2b  = (const float*)d_in[15];
  const float* bn3g  = (const float*)d_in[16];
  const float* bn3b  = (const float*)d_in[17];
  const float* rs1w  = (const float*)d_in[18];
  const float* rs1b  = (const float*)d_in[19];
  const float* fcw   = (const float*)d_in[20];
  const float* fcb   = (const float*)d_in[21];
  float* out = (float*)d_out;

  char* ws = (char*)d_ws;
  size_t off = 0;
  auto alloc = [&](size_t bytes) -> char* {
    char* p = ws + off;
    off = (off + bytes + 255) & ~(size_t)255;
    return p;
  };

  // total ws footprint ~470 MB (known-good <=484; 738 aborted in round 7)
  float* A_adj = (float*)alloc(441 * 4);
  f16* W1T  = (f16*)alloc((size_t)1024 * 512 * 2);
  f16* RS1T = (f16*)alloc((size_t)1024 * 512 * 2);
  f16* W2T  = (f16*)alloc((size_t)1024 * 1024 * 2);
  f16* W3T  = (f16*)alloc((size_t)512 * 1024 * 2);
  f16* FCWT = (f16*)alloc((size_t)1024 * 512 * 2);
  float* psum = (float*)alloc((size_t)NB * 1024 * 4);    // 16MB
  float* psq  = (float*)alloc((size_t)NB * 1024 * 4);    // 16MB
  float* rsum = (float*)alloc((size_t)32 * 1024 * 4);
  float* rsq  = (float*)alloc((size_t)32 * 1024 * 4);
  float* sc1 = (float*)alloc(1024 * 4);
  float* sh1 = (float*)alloc(1024 * 4);
  float* sc2 = (float*)alloc(1024 * 4);
  float* sh2 = (float*)alloc(1024 * 4);
  float* sc3 = (float*)alloc(1024 * 4);
  float* sh3 = (float*)alloc(1024 * 4);
  f16* pooled = (f16*)alloc((size_t)NB * 512 * 2);
  f16* G = (f16*)alloc((size_t)MROWS * 512 * 2);     // xg -> xgm -> T3
  f16* R = (f16*)alloc((size_t)MROWS * 1024 * 2);    // R1 -> h1
  f16* T = (f16*)alloc((size_t)MROWS * 1024 * 2);    // T1 -> T2/t2m -> h2m
  (void)ws_size; (void)in_sizes; (void)n_in; (void)out_size;

  // adjacency + batched weight transposes (1 launch)
  k_adj<<<1, 512, 0, stream>>>(nv1, nv2, A_adj);
  k_transpose_all<<<3072, dim3(32, 8), 0, stream>>>(W1, rs1w, W2, W3, fcw,
                                                    W1T, RS1T, W2T, W3T, FCWT);

  // fused SE path (mean + se1 + se2 + gate)
  k_segate<<<512, 256, 0, stream>>>(x, se_w1, se_w2, G);

  // layer 1: R1 = xg@rs1w; xgm = mix(xg) in place; T1 = xgm@W1 (+fused stats)
  // M-tiles = 86016/256 = 336; N=1024 -> 4 N-tiles (lgn=2) -> 1344 blocks
  k_gemm256<0><<<1344, 512, 0, stream>>>(G, RS1T, R, nullptr, nullptr, nullptr, nullptr, 1024, 512, 2);
  k_mixip<<<NB, 256, 0, stream>>>(G, A_adj);
  k_gemm256<1><<<1344, 512, 0, stream>>>(G, W1T, T, nullptr, nullptr, psum, psq, 1024, 512, 2);
  k_bnfuse<<<4, 256, 0, stream>>>(psum, psq, bn1g, bn1b, rs1b, sc1, sh1, 1024, 336);
  k_finalize<<<43008, 256, 0, stream>>>(T, R, R, sc1, sh1, 1023);     // h1 -> R

  // layer 2: T2 = h1@W2; mix+stats in place; h2m = mix(relu(BN(t2m)+h1)) -> T
  k_gemm256<0><<<1344, 512, 0, stream>>>(R, W2T, T, nullptr, nullptr, nullptr, nullptr, 1024, 1024, 2);
  k_mix<<<dim3(NB, 2), 256, 0, stream>>>(T, A_adj, psum, psq, 1024);
  k_reduce<<<dim3(4, 32), 256, 0, stream>>>(psum, psq, rsum, rsq, 1024, 128);
  k_bnfuse<<<4, 256, 0, stream>>>(rsum, rsq, bn2g, bn2b, nullptr, sc2, sh2, 1024, 32);
  k_finmix<<<dim3(NB, 2), 256, 0, stream>>>(T, R, nullptr, T, sc2, sh2, A_adj, 1024);

  // layer 3: T3 = h2m@W3 (+fused stats) -> G ; N=512 -> 2 N-tiles (lgn=1)
  k_gemm256<1><<<672, 512, 0, stream>>>(T, W3T, G, nullptr, nullptr, psum, psq, 512, 1024, 1);
  k_bnfuse<<<2, 256, 0, stream>>>(psum, psq, bn3g, bn3b, nullptr, sc3, sh3, 512, 336);

  // pool + fc : M=4096 -> 16 m-tiles x 4 n-tiles = 64 blocks
  k_pool<<<NB, 256, 0, stream>>>(G, sc3, sh3, pooled);
  k_gemm256<2><<<64, 512, 0, stream>>>(pooled, FCWT, nullptr, fcb, out, nullptr, nullptr, 1024, 512, 2);
}

// Round 14
// 1198.181 us; speedup vs baseline: 1.0675x; 1.0675x over previous
//
#include <hip/hip_runtime.h>

typedef _Float16 f16;
typedef f16 f16x2 __attribute__((ext_vector_type(2)));
typedef f16 f16x4 __attribute__((ext_vector_type(4)));
typedef f16 f16x8 __attribute__((ext_vector_type(8)));
typedef float f32x4 __attribute__((ext_vector_type(4)));
typedef const void __attribute__((address_space(1)))* gas1;
typedef void __attribute__((address_space(3)))* las3;

#define NB 4096
#define NN 21
#define MROWS (NB*NN)      // 86016
#define CIN 512

// ---------------- adjacency ----------------
__global__ void k_adj(const float* __restrict__ nv1, const float* __restrict__ nv2,
                      float* __restrict__ Aout) {
  __shared__ float at[21][21];
  __shared__ float dinv[21];
  int t = threadIdx.x;
  if (t < 441) {
    int i = t / 21, j = t % 21;
    float s = 0.f;
    #pragma unroll
    for (int r = 0; r < 10; r++) s += nv1[i*10 + r] * nv2[r*21 + j];
    float v = 1.f / (1.f + expf(-s));
    if (i == j) v += 1.f;
    at[i][j] = v;
  }
  __syncthreads();
  if (t < 21) {
    float d = 0.f;
    #pragma unroll
    for (int j = 0; j < 21; j++) d += at[t][j];
    dinv[t] = d > 0.f ? rsqrtf(d) : 0.f;
  }
  __syncthreads();
  if (t < 441) {
    int i = t / 21, j = t % 21;
    float a = dinv[i] * at[i][j] * dinv[j];
    Aout[t] = a > 0.1f ? a : 0.f;
  }
}

// ------- batched transpose: all 5 weight matrices in one launch -------
__global__ void k_transpose_all(const float* __restrict__ s0, const float* __restrict__ s1,
                                const float* __restrict__ s2, const float* __restrict__ s3,
                                const float* __restrict__ s4,
                                f16* __restrict__ d0, f16* __restrict__ d1,
                                f16* __restrict__ d2, f16* __restrict__ d3,
                                f16* __restrict__ d4) {
  __shared__ float tile[32][33];
  int b = blockIdx.x;
  const float* src; f16* dst; int K, N, local;
  if (b < 512)       { src = s0; dst = d0; K = 512;  N = 1024; local = b; }
  else if (b < 1024) { src = s1; dst = d1; K = 512;  N = 1024; local = b - 512; }
  else if (b < 2048) { src = s2; dst = d2; K = 1024; N = 1024; local = b - 1024; }
  else if (b < 2560) { src = s3; dst = d3; K = 1024; N = 512;  local = b - 2048; }
  else               { src = s4; dst = d4; K = 512;  N = 1024; local = b - 2560; }
  int ntn = N >> 5;
  int n0 = (local % ntn) * 32, k0 = (local / ntn) * 32;
  int tx = threadIdx.x, ty = threadIdx.y;
  #pragma unroll
  for (int i = 0; i < 4; i++)
    tile[ty + 8*i][tx] = src[(size_t)(k0 + ty + 8*i) * N + n0 + tx];
  __syncthreads();
  #pragma unroll
  for (int i = 0; i < 4; i++)
    dst[(size_t)(n0 + ty + 8*i) * K + k0 + tx] = (f16)tile[tx][ty + 8*i];
}

// ---------------- node mean over 21 ----------------
__global__ void k_mean(const float* __restrict__ x, float* __restrict__ xm) {
  int b = blockIdx.x, t = threadIdx.x;
  for (int c = t; c < CIN; c += 256) {
    float s = 0.f;
    #pragma unroll
    for (int n = 0; n < NN; n++) s += x[((size_t)b*NN + n)*CIN + c];
    xm[(size_t)b*CIN + c] = s * (1.f/21.f);
  }
}

// ---------------- SE matmuls ----------------
__global__ void k_se1(const float* __restrict__ xm, const float* __restrict__ w1,
                      float* __restrict__ y1) {
  __shared__ float row[CIN];
  int b = blockIdx.x, t = threadIdx.x;   // 128 threads
  for (int k = t; k < CIN; k += 128) row[k] = xm[(size_t)b*CIN + k];
  __syncthreads();
  float acc = 0.f;
  for (int k = 0; k < CIN; k++) acc += row[k] * w1[(size_t)k*128 + t];
  y1[(size_t)b*128 + t] = fmaxf(acc, 0.f);
}

__global__ void k_se2(const float* __restrict__ y1, const float* __restrict__ w2,
                      float* __restrict__ y) {
  __shared__ float row[128];
  int b = blockIdx.x, t = threadIdx.x;   // 512 threads
  if (t < 128) row[t] = y1[(size_t)b*128 + t];
  __syncthreads();
  float acc = 0.f;
  for (int k = 0; k < 128; k++) acc += row[k] * w2[(size_t)k*CIN + t];
  y[(size_t)b*CIN + t] = 1.f / (1.f + expf(-acc));
}

// ---------------- gating: xg = f16(x * y[graph]) ----------------
__global__ void k_gate(const float* __restrict__ x, const float* __restrict__ y,
                       f16* __restrict__ xg) {
  size_t i8 = (size_t)blockIdx.x * 256 + threadIdx.x;
  size_t base = i8 * 8;
  int r = (int)(base >> 9);          // /512
  int c = (int)(base & 511);
  int b = r / 21;
  const float4* xp = (const float4*)(x + base);
  const float4* yp = (const float4*)(y + (size_t)b*CIN + c);
  float4 a0 = xp[0], a1 = xp[1];
  float4 g0 = yp[0], g1 = yp[1];
  f16x8 o;
  o[0] = (f16)(a0.x * g0.x); o[1] = (f16)(a0.y * g0.y);
  o[2] = (f16)(a0.z * g0.z); o[3] = (f16)(a0.w * g0.w);
  o[4] = (f16)(a1.x * g1.x); o[5] = (f16)(a1.y * g1.y);
  o[6] = (f16)(a1.z * g1.z); o[7] = (f16)(a1.w * g1.w);
  *(f16x8*)(xg + base) = o;
}

// ======== 256x256 8-wave GEMM, slice-major LDS + counted-vmcnt phases ========
// r10/r11/r12 localized the stall: drain-0 exposes ~900cy HBM latency/tile;
// counted wait needs the NEXT tile's loads in flight at the wait, impossible
// with row-major halves (every phase reads all rows). Fix: k-SLICE-major LDS
// (buffer = [s][mat][row][64B]); phases 0-1 read slice0 only, 2-3 slice1 ->
// stage (t+1)H1 during ph0-1 and (t+2)H0 during ph2-3 (region freed by the
// mid-tile barrier). Waits: mid vmcnt(8) [(t)H1 landed], end vmcnt(8)
// [(t+1)H0 landed] - targets issued >=2 phases (~1200cy) earlier -> ~0 stall.
// Epilogue degrades to vmcnt(4)/vmcnt(0) by guard. Bank swizzle for 64B rows:
// granule ^= (row^(row>>2))&3 -> 2-way aliasing only (free, m136).
// BK=64, 2x64KB LDS, 8 waves (2Mx4N), per-wave 128x64 (acc[8][4]).
// Swapped operands (mfma(bv,av)) -> vectorized f16x4/float4 C-stores.
// MODE 0: f16 out. MODE 1: + fused BN column-stat partials. MODE 2: f32+bias.
#define QBUF 65536

template<int MODE>
__global__ __launch_bounds__(512, 1)
void k_gemm256(const f16* __restrict__ A, const f16* __restrict__ BT,
               f16* __restrict__ C1, const float* __restrict__ bias,
               float* __restrict__ Cf, float* __restrict__ psum,
               float* __restrict__ psq, int N, int K, int lgn) {
  __shared__ __align__(16) char lds[2 * QBUF];
  const int tid = threadIdx.x;
  const int nwg = gridDim.x;
  const int g = blockIdx.x;
  const int swz = (g & 7) * (nwg >> 3) + (g >> 3);   // XCD-chunked, nwg%8==0
  const int bn = swz & ((1 << lgn) - 1);             // N fastest: A-panel L2 reuse
  const int bm = swz >> lgn;
  const int lane = tid & 63;
  const int wid = tid >> 6;
  const int wr = wid >> 2;          // 0..1 : 128-row half
  const int wc = wid & 3;           // 0..3 : 64-col slab
  const int fr = lane & 15;
  const int kg = lane >> 4;         // 0..3

  // staging: j=0..7: s=j>>2, mat=(j>>1)&1, jj=j&1. Within-buffer LDS layout:
  // off = s*32768 + mat*16384 + row*64 + gr*16 (linear in gid). Source granule
  // pre-swizzled gsw = gr ^ ((row^(row>>2))&3).
  int srcOff[8]; int ldsOff[8];
  #pragma unroll
  for (int j = 0; j < 8; j++) {
    int s = j >> 2, mat = (j >> 1) & 1, jj = j & 1;
    int idx = jj * 512 + tid;       // 0..1023
    int row = idx >> 2;             // 0..255
    int gr  = tid & 3;
    int gsw = gr ^ ((row ^ (row >> 2)) & 3);
    srcOff[j] = ((mat ? bn : bm) * 256 + row) * K + s*32 + gsw*8;
    ldsOff[j] = s*32768 + mat*16384 + idx*16;
  }

  int aOff[8], axor[8], bOff[4], bxor[4];
  #pragma unroll
  for (int m = 0; m < 8; m++) {
    int row = wr*128 + m*16 + fr;
    aOff[m] = row * 64; axor[m] = (row ^ (row >> 2)) & 3;
  }
  #pragma unroll
  for (int n = 0; n < 4; n++) {
    int row = wc*64 + n*16 + fr;
    bOff[n] = 16384 + row * 64; bxor[n] = (row ^ (row >> 2)) & 3;
  }

  f32x4 acc[8][4];
  #pragma unroll
  for (int m = 0; m < 8; m++)
    #pragma unroll
    for (int n = 0; n < 4; n++)
      #pragma unroll
      for (int r = 0; r < 4; r++) acc[m][n][r] = 0.f;

  auto STAGE2 = [&](int t2, int sbuf, int j0) {   // 2 wave-loads = 16 KB
    char* dst = (char*)lds + sbuf * QBUF;
    const size_t kof = (size_t)t2 * 64;
    #pragma unroll
    for (int j = j0; j < j0 + 2; j++) {
      const f16* src = (((j >> 1) & 1) ? BT : A) + srcOff[j] + kof;
      __builtin_amdgcn_global_load_lds((gas1)src, (las3)(dst + ldsOff[j]), 16, 0, 0);
    }
  };
  auto READB = [&](f16x8* bv, const char* rb, int s) {
    #pragma unroll
    for (int n = 0; n < 4; n++)
      bv[n] = *(const f16x8*)(rb + s*32768 + bOff[n] + ((kg ^ bxor[n]) << 4));
  };
  auto READA4 = [&](f16x8* av, const char* rb, int s, int mh) {
    #pragma unroll
    for (int mi = 0; mi < 4; mi++)
      av[mi] = *(const f16x8*)(rb + s*32768 + aOff[mh*4 + mi] + ((kg ^ axor[mh*4 + mi]) << 4));
  };

  const int NT = K >> 6;            // >= 8 for all our shapes
  // prologue: (0)H0, (0)H1, (1)H0 ; wait (0)H0 landed (8 newer in flight)
  STAGE2(0, 0, 0); STAGE2(0, 0, 2);       // (0)H0 : slice0 A,B
  STAGE2(0, 0, 4); STAGE2(0, 0, 6);       // (0)H1 : slice1 A,B
  STAGE2(1, 1, 0); STAGE2(1, 1, 2);       // (1)H0
  asm volatile("s_waitcnt vmcnt(8)" ::: "memory");
  asm volatile("s_barrier" ::: "memory");

  for (int t = 0; t < NT; t++) {
    const char* rb = (const char*)lds + (t & 1) * QBUF;
    const int nb  = (t + 1) & 1;
    const int nb2 = t & 1;
    const bool s1 = (t + 1) < NT;
    const bool s2 = (t + 2) < NT;
    f16x8 av[4], bv[4];

    // ph0: slice0, m-half 0 ; stage (t+1)H1 A-part
    READB(bv, rb, 0); READA4(av, rb, 0, 0);
    if (s1) STAGE2(t + 1, nb, 4);
    __builtin_amdgcn_s_setprio(1);
    #pragma unroll
    for (int mi = 0; mi < 4; mi++)
      #pragma unroll
      for (int n = 0; n < 4; n++)
        acc[mi][n] = __builtin_amdgcn_mfma_f32_16x16x32_f16(bv[n], av[mi], acc[mi][n], 0, 0, 0);
    __builtin_amdgcn_s_setprio(0);
    __builtin_amdgcn_sched_barrier(0);

    // ph1: slice0, m-half 1 ; stage (t+1)H1 B-part
    READA4(av, rb, 0, 1);
    if (s1) STAGE2(t + 1, nb, 6);
    __builtin_amdgcn_s_setprio(1);
    #pragma unroll
    for (int mi = 0; mi < 4; mi++)
      #pragma unroll
      for (int n = 0; n < 4; n++)
        acc[4 + mi][n] = __builtin_amdgcn_mfma_f32_16x16x32_f16(bv[n], av[mi], acc[4 + mi][n], 0, 0, 0);
    __builtin_amdgcn_s_setprio(0);
    __builtin_amdgcn_sched_barrier(0);

    // mid: (t)H1 must be resident; newer in flight = (t+1)H0+(t+1)H1 = 8
    if (s1) asm volatile("s_waitcnt vmcnt(8)" ::: "memory");
    else    asm volatile("s_waitcnt vmcnt(0)" ::: "memory");
    asm volatile("s_barrier" ::: "memory");     // slice0 reads retired block-wide

    // ph2: slice1, m-half 0 ; stage (t+2)H0 A-part (into freed slice0 region)
    READB(bv, rb, 1); READA4(av, rb, 1, 0);
    if (s2) STAGE2(t + 2, nb2, 0);
    __builtin_amdgcn_s_setprio(1);
    #pragma unroll
    for (int mi = 0; mi < 4; mi++)
      #pragma unroll
      for (int n = 0; n < 4; n++)
        acc[mi][n] = __builtin_amdgcn_mfma_f32_16x16x32_f16(bv[n], av[mi], acc[mi][n], 0, 0, 0);
    __builtin_amdgcn_s_setprio(0);
    __builtin_amdgcn_sched_barrier(0);

    // ph3: slice1, m-half 1 ; stage (t+2)H0 B-part
    READA4(av, rb, 1, 1);
    if (s2) STAGE2(t + 2, nb2, 2);
    __builtin_amdgcn_s_setprio(1);
    #pragma unroll
    for (int mi = 0; mi < 4; mi++)
      #pragma unroll
      for (int n = 0; n < 4; n++)
        acc[4 + mi][n] = __builtin_amdgcn_mfma_f32_16x16x32_f16(bv[n], av[mi], acc[4 + mi][n], 0, 0, 0);
    __builtin_amdgcn_s_setprio(0);
    __builtin_amdgcn_sched_barrier(0);

    // end: (t+1)H0 must be resident; newer = (t+1)H1 (+ (t+2)H0 if staged)
    if (s1) {
      if (s2) asm volatile("s_waitcnt vmcnt(8)" ::: "memory");
      else    asm volatile("s_waitcnt vmcnt(4)" ::: "memory");
      asm volatile("s_barrier" ::: "memory");   // slice1 reads retired block-wide
    }
  }

  // swapped-operand C layout: C[bm*256 + wr*128 + m*16 + fr]
  //                            [bn*256 + wc*64 + n*16 + kg*4 + r]
  const int crow = bm*256 + wr*128 + fr;    // + m*16
  const int ccol = bn*256 + wc*64 + kg*4;   // + n*16, r contiguous
  if constexpr (MODE == 2) {
    #pragma unroll
    for (int n = 0; n < 4; n++) {
      float4 bb = *(const float4*)(bias + ccol + n*16);
      #pragma unroll
      for (int m = 0; m < 8; m++) {
        float4 v;
        v.x = acc[m][n][0] + bb.x; v.y = acc[m][n][1] + bb.y;
        v.z = acc[m][n][2] + bb.z; v.w = acc[m][n][3] + bb.w;
        *(float4*)(Cf + (size_t)(crow + m*16) * N + ccol + n*16) = v;
      }
    }
  } else {
    #pragma unroll
    for (int m = 0; m < 8; m++)
      #pragma unroll
      for (int n = 0; n < 4; n++) {
        f16x4 o;
        o[0] = (f16)acc[m][n][0]; o[1] = (f16)acc[m][n][1];
        o[2] = (f16)acc[m][n][2]; o[3] = (f16)acc[m][n][3];
        *(f16x4*)(C1 + (size_t)(crow + m*16) * N + ccol + n*16) = o;
      }
  }
  if constexpr (MODE == 1) {
    float s[4][4], q[4][4];
    #pragma unroll
    for (int n = 0; n < 4; n++)
      #pragma unroll
      for (int r = 0; r < 4; r++) {
        float ss = 0.f, qq = 0.f;
        #pragma unroll
        for (int m = 0; m < 8; m++) { float v = acc[m][n][r]; ss += v; qq = fmaf(v, v, qq); }
        s[n][r] = ss; q[n][r] = qq;
      }
    #pragma unroll
    for (int n = 0; n < 4; n++)
      #pragma unroll
      for (int r = 0; r < 4; r++) {
        s[n][r] += __shfl_xor(s[n][r], 1); s[n][r] += __shfl_xor(s[n][r], 2);
        s[n][r] += __shfl_xor(s[n][r], 4); s[n][r] += __shfl_xor(s[n][r], 8);
        q[n][r] += __shfl_xor(q[n][r], 1); q[n][r] += __shfl_xor(q[n][r], 2);
        q[n][r] += __shfl_xor(q[n][r], 4); q[n][r] += __shfl_xor(q[n][r], 8);
      }
    float* wred = (float*)lds;   // 4 KB scratch; all staging drained (last mid wait = 0)
    __syncthreads();
    if (fr == 0) {
      #pragma unroll
      for (int n = 0; n < 4; n++)
        #pragma unroll
        for (int r = 0; r < 4; r++) {
          int c = wc*64 + n*16 + kg*4 + r;
          wred[wr*256 + c]       = s[n][r];
          wred[512 + wr*256 + c] = q[n][r];
        }
    }
    __syncthreads();
    if (tid < 256) {
      psum[(size_t)bm * N + bn*256 + tid] = wred[tid]       + wred[256 + tid];
      psq [(size_t)bm * N + bn*256 + tid] = wred[512 + tid] + wred[768 + tid];
    }
  }
}

// ---------------- in-place mix on [M][512] (xg -> mix(xg)) ----------------
__global__ __launch_bounds__(256)
void k_mixip(f16* __restrict__ t, const float* __restrict__ Aadj) {
  __shared__ float A[441];
  int b = blockIdx.x, tid = threadIdx.x;
  for (int i = tid; i < 441; i += 256) A[i] = Aadj[i];
  __syncthreads();
  int c0 = tid * 2;
  size_t base = (size_t)b * NN * 512 + c0;
  float vx[21], vy[21];
  #pragma unroll
  for (int j = 0; j < 21; j++) {
    f16x2 v = *(const f16x2*)(t + base + (size_t)j * 512);
    vx[j] = (float)v[0]; vy[j] = (float)v[1];
  }
  #pragma unroll
  for (int i = 0; i < 21; i++) {
    float a0 = 0.f, a1 = 0.f;
    #pragma unroll
    for (int j = 0; j < 21; j++) { float w = A[i*21+j]; a0 = fmaf(w, vx[j], a0); a1 = fmaf(w, vy[j], a1); }
    f16x2 o; o[0] = (f16)a0; o[1] = (f16)a1;
    *(f16x2*)(t + base + (size_t)i * 512) = o;
  }
}

// ------- per-graph 21x21 mix, in-place + per-graph BN stats -------
__global__ __launch_bounds__(256)
void k_mix(f16* __restrict__ t, const float* __restrict__ Aadj,
           float* __restrict__ psum, float* __restrict__ psq, int C) {
  __shared__ float A[441];
  int b = blockIdx.x, tid = threadIdx.x;
  for (int i = tid; i < 441; i += 256) A[i] = Aadj[i];
  __syncthreads();
  int c0 = (blockIdx.y * 256 + tid) * 2;
  size_t base = (size_t)b * NN * C + c0;
  float vx[21], vy[21];
  #pragma unroll
  for (int j = 0; j < 21; j++) {
    f16x2 v = *(const f16x2*)(t + base + (size_t)j * C);
    vx[j] = (float)v[0]; vy[j] = (float)v[1];
  }
  float s0 = 0.f, s1 = 0.f, q0 = 0.f, q1 = 0.f;
  #pragma unroll
  for (int i = 0; i < 21; i++) {
    float a0 = 0.f, a1 = 0.f;
    #pragma unroll
    for (int j = 0; j < 21; j++) {
      float w = A[i*21 + j];
      a0 = fmaf(w, vx[j], a0);
      a1 = fmaf(w, vy[j], a1);
    }
    f16x2 o; o[0] = (f16)a0; o[1] = (f16)a1;
    *(f16x2*)(t + base + (size_t)i * C) = o;
    s0 += a0; s1 += a1;
    q0 = fmaf(a0, a0, q0); q1 = fmaf(a1, a1, q1);
  }
  float2 sv; sv.x = s0; sv.y = s1;
  float2 qv; qv.x = q0; qv.y = q1;
  *(float2*)(psum + (size_t)b * C + c0) = sv;
  *(float2*)(psq  + (size_t)b * C + c0) = qv;
}

// ---------------- reduce partials -> groups (deterministic) --------------
__global__ void k_reduce(const float* __restrict__ ps, const float* __restrict__ pq,
                         float* __restrict__ rs, float* __restrict__ rq,
                         int C, int per) {
  int c = blockIdx.x * 256 + threadIdx.x;
  int py = blockIdx.y;
  float s = 0.f, q = 0.f;
  for (int p = py*per; p < py*per + per; p++) {
    s += ps[(size_t)p*C + c];
    q += pq[(size_t)p*C + c];
  }
  rs[(size_t)py*C + c] = s;
  rq[(size_t)py*C + c] = q;
}

__global__ void k_bnparams(const float* __restrict__ psum, const float* __restrict__ psq,
                           const float* __restrict__ gamma, const float* __restrict__ beta,
                           const float* __restrict__ resbias,
                           float* __restrict__ scale, float* __restrict__ shift,
                           int C, int npart) {
  int c = blockIdx.x * 256 + threadIdx.x;
  float s = 0.f, q = 0.f;
  for (int p = 0; p < npart; p++) { s += psum[(size_t)p*C + c]; q += psq[(size_t)p*C + c]; }
  const float Minv = 1.f / (float)MROWS;
  float mean = s * Minv;
  float var = q * Minv - mean * mean;
  float sc = gamma[c] * rsqrtf(var + 1e-5f);
  float sh = beta[c] - mean * sc;
  if (resbias) sh += resbias[c];
  scale[c] = sc; shift[c] = sh;
}

// ---------------- finalize: dst = relu(g*scale + shift + res) ----------------
__global__ void k_finalize(const f16* __restrict__ g, const f16* res,
                           f16* dst, const float* __restrict__ scale,
                           const float* __restrict__ shift, int cmask) {
  size_t i8 = (size_t)blockIdx.x * 256 + threadIdx.x;
  size_t base = i8 * 8;
  int c = (int)(base & (size_t)cmask);
  f16x8 gv = *(const f16x8*)(g + base);
  f16x8 rv = *(const f16x8*)(res + base);
  f16x8 o;
  #pragma unroll
  for (int j = 0; j < 8; j++) {
    float v = (float)gv[j] * scale[c + j] + shift[c + j] + (float)rv[j];
    o[j] = (f16)fmaxf(v, 0.f);
  }
  *(f16x8*)(dst + base) = o;
}

// ---------------- fused finish + mix: hmix = mix(relu(t*sc+sh+res)) ---------
__global__ __launch_bounds__(256)
void k_finmix(const f16* t, const f16* res, f16* hout, f16* hmix,
              const float* __restrict__ scale, const float* __restrict__ shift,
              const float* __restrict__ Aadj, int C) {
  __shared__ float A[441];
  int b = blockIdx.x, tid = threadIdx.x;
  for (int i = tid; i < 441; i += 256) A[i] = Aadj[i];
  __syncthreads();
  int c0 = (blockIdx.y * 256 + tid) * 2;
  float scx = scale[c0], scy = scale[c0+1];
  float shx = shift[c0], shy = shift[c0+1];
  size_t base = (size_t)b * NN * C + c0;
  float hx[21], hy[21];
  #pragma unroll
  for (int j = 0; j < 21; j++) {
    f16x2 tv = *(const f16x2*)(t + base + (size_t)j*C);
    f16x2 rv = *(const f16x2*)(res + base + (size_t)j*C);
    hx[j] = fmaxf((float)tv[0]*scx + shx + (float)rv[0], 0.f);
    hy[j] = fmaxf((float)tv[1]*scy + shy + (float)rv[1], 0.f);
    if (hout) {
      f16x2 o; o[0] = (f16)hx[j]; o[1] = (f16)hy[j];
      *(f16x2*)(hout + base + (size_t)j*C) = o;
    }
  }
  #pragma unroll
  for (int i = 0; i < 21; i++) {
    float a0 = 0.f, a1 = 0.f;
    #pragma unroll
    for (int j = 0; j < 21; j++) { float w = A[i*21+j]; a0 = fmaf(w, hx[j], a0); a1 = fmaf(w, hy[j], a1); }
    f16x2 o; o[0] = (f16)a0; o[1] = (f16)a1;
    *(f16x2*)(hmix + base + (size_t)i*C) = o;
  }
}

// ---------------- pool (mean over 21) + BN affine -> f16 ----------------
__global__ void k_pool(const f16* __restrict__ g3, const float* __restrict__ scale,
                       const float* __restrict__ shift, f16* __restrict__ pooled) {
  int b = blockIdx.x, t = threadIdx.x;
  for (int c = t; c < 512; c += 256) {
    float s = 0.f;
    #pragma unroll
    for (int n = 0; n < NN; n++) s += (float)g3[((size_t)b*NN + n)*512 + c];
    pooled[(size_t)b*512 + c] = (f16)((s * (1.f/21.f)) * scale[c] + shift[c]);
  }
}

extern "C" void kernel_launch(void* const* d_in, const int* in_sizes, int n_in,
                              void* d_out, int out_size, void* d_ws, size_t ws_size,
                              hipStream_t stream) {
  const float* x     = (const float*)d_in[0];
  const float* nv1   = (const float*)d_in[2];
  const float* nv2   = (const float*)d_in[3];
  const float* se_w1 = (const float*)d_in[4];
  const float* se_w2 = (const float*)d_in[5];
  const float* W1    = (const float*)d_in[6];
  const float* W2    = (const float*)d_in[8];
  const float* W3    = (const float*)d_in[10];
  const float* bn1g  = (const float*)d_in[12];
  const float* bn1b  = (const float*)d_in[13];
  const float* bn2g  = (const float*)d_in[14];
  const float* bn2b  = (const float*)d_in[15];
  const float* bn3g  = (const float*)d_in[16];
  const float* bn3b  = (const float*)d_in[17];
  const float* rs1w  = (const float*)d_in[18];
  const float* rs1b  = (const float*)d_in[19];
  const float* fcw   = (const float*)d_in[20];
  const float* fcb   = (const float*)d_in[21];
  float* out = (float*)d_out;

  char* ws = (char*)d_ws;
  size_t off = 0;
  auto alloc = [&](size_t bytes) -> char* {
    char* p = ws + off;
    off = (off + bytes + 255) & ~(size_t)255;
    return p;
  };

  // total ws footprint ~470 MB (known-good <=484; 738 aborted in round 7)
  float* A_adj = (float*)alloc(441 * 4);
  f16* W1T  = (f16*)alloc((size_t)1024 * 512 * 2);
  f16* RS1T = (f16*)alloc((size_t)1024 * 512 * 2);
  f16* W2T  = (f16*)alloc((size_t)1024 * 1024 * 2);
  f16* W3T  = (f16*)alloc((size_t)512 * 1024 * 2);
  f16* FCWT = (f16*)alloc((size_t)1024 * 512 * 2);
  float* psum = (float*)alloc((size_t)NB * 1024 * 4);    // 16MB; aliases xm
  float* psq  = (float*)alloc((size_t)NB * 1024 * 4);    // 16MB; aliases yv
  float* y1   = (float*)alloc((size_t)NB * 128 * 4);
  float* rsum = (float*)alloc((size_t)32 * 1024 * 4);
  float* rsq  = (float*)alloc((size_t)32 * 1024 * 4);
  float* sc1 = (float*)alloc(1024 * 4);
  float* sh1 = (float*)alloc(1024 * 4);
  float* sc2 = (float*)alloc(1024 * 4);
  float* sh2 = (float*)alloc(1024 * 4);
  float* sc3 = (float*)alloc(1024 * 4);
  float* sh3 = (float*)alloc(1024 * 4);
  f16* pooled = (f16*)alloc((size_t)NB * 512 * 2);
  f16* G = (f16*)alloc((size_t)MROWS * 512 * 2);     // xg -> xgm -> T3
  f16* R = (f16*)alloc((size_t)MROWS * 1024 * 2);    // R1 -> h1
  f16* T = (f16*)alloc((size_t)MROWS * 1024 * 2);    // T1 -> T2/t2m -> h2m
  float* xm = psum;   // dead before psum first written
  float* yv = psq;    // dead after k_gate, before psq first written
  (void)ws_size; (void)in_sizes; (void)n_in; (void)out_size;

  // adjacency + batched weight transposes (1 launch)
  k_adj<<<1, 512, 0, stream>>>(nv1, nv2, A_adj);
  k_transpose_all<<<3072, dim3(32, 8), 0, stream>>>(W1, rs1w, W2, W3, fcw,
                                                    W1T, RS1T, W2T, W3T, FCWT);

  // SE path + gate (r10 forms — r13's fused k_segate regressed ~100us)
  k_mean<<<NB, 256, 0, stream>>>(x, xm);
  k_se1<<<NB, 128, 0, stream>>>(xm, se_w1, y1);
  k_se2<<<NB, 512, 0, stream>>>(y1, se_w2, yv);
  k_gate<<<21504, 256, 0, stream>>>(x, yv, G);

  // layer 1: R1 = xg@rs1w; xgm = mix(xg) in place; T1 = xgm@W1 (+fused stats)
  // M-tiles = 86016/256 = 336; N=1024 -> 4 N-tiles (lgn=2) -> 1344 blocks
  k_gemm256<0><<<1344, 512, 0, stream>>>(G, RS1T, R, nullptr, nullptr, nullptr, nullptr, 1024, 512, 2);
  k_mixip<<<NB, 256, 0, stream>>>(G, A_adj);
  k_gemm256<1><<<1344, 512, 0, stream>>>(G, W1T, T, nullptr, nullptr, psum, psq, 1024, 512, 2);
  k_reduce<<<dim3(4, 24), 256, 0, stream>>>(psum, psq, rsum, rsq, 1024, 14);   // 24*14 = 336
  k_bnparams<<<4, 256, 0, stream>>>(rsum, rsq, bn1g, bn1b, rs1b, sc1, sh1, 1024, 24);
  k_finalize<<<43008, 256, 0, stream>>>(T, R, R, sc1, sh1, 1023);     // h1 -> R

  // layer 2: T2 = h1@W2; mix+stats in place; h2m = mix(relu(BN(t2m)+h1)) -> T
  k_gemm256<0><<<1344, 512, 0, stream>>>(R, W2T, T, nullptr, nullptr, nullptr, nullptr, 1024, 1024, 2);
  k_mix<<<dim3(NB, 2), 256, 0, stream>>>(T, A_adj, psum, psq, 1024);
  k_reduce<<<dim3(4, 32), 256, 0, stream>>>(psum, psq, rsum, rsq, 1024, 128);
  k_bnparams<<<4, 256, 0, stream>>>(rsum, rsq, bn2g, bn2b, nullptr, sc2, sh2, 1024, 32);
  k_finmix<<<dim3(NB, 2), 256, 0, stream>>>(T, R, nullptr, T, sc2, sh2, A_adj, 1024);

  // layer 3: T3 = h2m@W3 (+fused stats) -> G ; N=512 -> 2 N-tiles (lgn=1)
  k_gemm256<1><<<672, 512, 0, stream>>>(T, W3T, G, nullptr, nullptr, psum, psq, 512, 1024, 1);
  k_reduce<<<dim3(2, 24), 256, 0, stream>>>(psum, psq, rsum, rsq, 512, 14);
  k_bnparams<<<2, 256, 0, stream>>>(rsum, rsq, bn3g, bn3b, nullptr, sc3, sh3, 512, 24);

  // pool + fc : M=4096 -> 16 m-tiles x 4 n-tiles = 64 blocks
  k_pool<<<NB, 256, 0, stream>>>(G, sc3, sh3, pooled);
  k_gemm256<2><<<64, 512, 0, stream>>>(pooled, FCWT, nullptr, fcb, out, nullptr, nullptr, 1024, 512, 2);
}

// Round 15
// 1166.796 us; speedup vs baseline: 1.0962x; 1.0269x over previous
//
#include <hip/hip_runtime.h>

typedef _Float16 f16;
typedef f16 f16x2 __attribute__((ext_vector_type(2)));
typedef f16 f16x4 __attribute__((ext_vector_type(4)));
typedef f16 f16x8 __attribute__((ext_vector_type(8)));
typedef float f32x4 __attribute__((ext_vector_type(4)));
typedef const void __attribute__((address_space(1)))* gas1;
typedef void __attribute__((address_space(3)))* las3;

#define NB 4096
#define NN 21
#define MROWS (NB*NN)      // 86016
#define CIN 512

// ---------------- adjacency ----------------
__global__ void k_adj(const float* __restrict__ nv1, const float* __restrict__ nv2,
                      float* __restrict__ Aout) {
  __shared__ float at[21][21];
  __shared__ float dinv[21];
  int t = threadIdx.x;
  if (t < 441) {
    int i = t / 21, j = t % 21;
    float s = 0.f;
    #pragma unroll
    for (int r = 0; r < 10; r++) s += nv1[i*10 + r] * nv2[r*21 + j];
    float v = 1.f / (1.f + expf(-s));
    if (i == j) v += 1.f;
    at[i][j] = v;
  }
  __syncthreads();
  if (t < 21) {
    float d = 0.f;
    #pragma unroll
    for (int j = 0; j < 21; j++) d += at[t][j];
    dinv[t] = d > 0.f ? rsqrtf(d) : 0.f;
  }
  __syncthreads();
  if (t < 441) {
    int i = t / 21, j = t % 21;
    float a = dinv[i] * at[i][j] * dinv[j];
    Aout[t] = a > 0.1f ? a : 0.f;
  }
}

// ------- batched transpose: all 5 weight matrices in one launch -------
__global__ void k_transpose_all(const float* __restrict__ s0, const float* __restrict__ s1,
                                const float* __restrict__ s2, const float* __restrict__ s3,
                                const float* __restrict__ s4,
                                f16* __restrict__ d0, f16* __restrict__ d1,
                                f16* __restrict__ d2, f16* __restrict__ d3,
                                f16* __restrict__ d4) {
  __shared__ float tile[32][33];
  int b = blockIdx.x;
  const float* src; f16* dst; int K, N, local;
  if (b < 512)       { src = s0; dst = d0; K = 512;  N = 1024; local = b; }
  else if (b < 1024) { src = s1; dst = d1; K = 512;  N = 1024; local = b - 512; }
  else if (b < 2048) { src = s2; dst = d2; K = 1024; N = 1024; local = b - 1024; }
  else if (b < 2560) { src = s3; dst = d3; K = 1024; N = 512;  local = b - 2048; }
  else               { src = s4; dst = d4; K = 512;  N = 1024; local = b - 2560; }
  int ntn = N >> 5;
  int n0 = (local % ntn) * 32, k0 = (local / ntn) * 32;
  int tx = threadIdx.x, ty = threadIdx.y;
  #pragma unroll
  for (int i = 0; i < 4; i++)
    tile[ty + 8*i][tx] = src[(size_t)(k0 + ty + 8*i) * N + n0 + tx];
  __syncthreads();
  #pragma unroll
  for (int i = 0; i < 4; i++)
    dst[(size_t)(n0 + ty + 8*i) * K + k0 + tx] = (f16)tile[tx][ty + 8*i];
}

// ---------------- node mean over 21 ----------------
__global__ void k_mean(const float* __restrict__ x, float* __restrict__ xm) {
  int b = blockIdx.x, t = threadIdx.x;
  for (int c = t; c < CIN; c += 256) {
    float s = 0.f;
    #pragma unroll
    for (int n = 0; n < NN; n++) s += x[((size_t)b*NN + n)*CIN + c];
    xm[(size_t)b*CIN + c] = s * (1.f/21.f);
  }
}

// ---------------- SE matmuls ----------------
__global__ void k_se1(const float* __restrict__ xm, const float* __restrict__ w1,
                      float* __restrict__ y1) {
  __shared__ float row[CIN];
  int b = blockIdx.x, t = threadIdx.x;   // 128 threads
  for (int k = t; k < CIN; k += 128) row[k] = xm[(size_t)b*CIN + k];
  __syncthreads();
  float acc = 0.f;
  for (int k = 0; k < CIN; k++) acc += row[k] * w1[(size_t)k*128 + t];
  y1[(size_t)b*128 + t] = fmaxf(acc, 0.f);
}

__global__ void k_se2(const float* __restrict__ y1, const float* __restrict__ w2,
                      float* __restrict__ y) {
  __shared__ float row[128];
  int b = blockIdx.x, t = threadIdx.x;   // 512 threads
  if (t < 128) row[t] = y1[(size_t)b*128 + t];
  __syncthreads();
  float acc = 0.f;
  for (int k = 0; k < 128; k++) acc += row[k] * w2[(size_t)k*CIN + t];
  y[(size_t)b*CIN + t] = 1.f / (1.f + expf(-acc));
}

// ---------------- gating: xg = f16(x * y[graph]) ----------------
__global__ void k_gate(const float* __restrict__ x, const float* __restrict__ y,
                       f16* __restrict__ xg) {
  size_t i8 = (size_t)blockIdx.x * 256 + threadIdx.x;
  size_t base = i8 * 8;
  int r = (int)(base >> 9);          // /512
  int c = (int)(base & 511);
  int b = r / 21;
  const float4* xp = (const float4*)(x + base);
  const float4* yp = (const float4*)(y + (size_t)b*CIN + c);
  float4 a0 = xp[0], a1 = xp[1];
  float4 g0 = yp[0], g1 = yp[1];
  f16x8 o;
  o[0] = (f16)(a0.x * g0.x); o[1] = (f16)(a0.y * g0.y);
  o[2] = (f16)(a0.z * g0.z); o[3] = (f16)(a0.w * g0.w);
  o[4] = (f16)(a1.x * g1.x); o[5] = (f16)(a1.y * g1.y);
  o[6] = (f16)(a1.z * g1.z); o[7] = (f16)(a1.w * g1.w);
  *(f16x8*)(xg + base) = o;
}

// ======== 256x256 8-wave GEMM (r10 schedule — best measured) ========
// BK=64, dbuf 2x64KB LDS, 8 waves (2Mx4N), per-wave 128x64 out (acc[8][4]).
// Staging split into 4 half-stages interleaved with the 2 MFMA clusters;
// vmcnt(0)+1 barrier per K-tile. MFMA operands swapped (mfma(bv,av)) -> 4
// consecutive C-cols per acc reg -> vectorized f16x4/float4 stores.
// T2 granule-XOR swizzle on global source + ds_read (LDS dest linear).
// Schedule exploration closed: r11 counted/serial (-20%), r12 4-phase
// interleave (=), r14 slice-major counted (+bank conflicts, -5%) all fail
// to beat this; ~33-35% MfmaUtil is the 2-phase-family HIP plateau.
// MODE 0: f16 out. MODE 1: f16 out + fused BN column-stat partials per m-block.
// MODE 2: f32 out + bias.
#define QBUF 65536

template<int MODE>
__global__ __launch_bounds__(512, 1)
void k_gemm256(const f16* __restrict__ A, const f16* __restrict__ BT,
               f16* __restrict__ C1, const float* __restrict__ bias,
               float* __restrict__ Cf, float* __restrict__ psum,
               float* __restrict__ psq, int N, int K, int lgn) {
  __shared__ __align__(16) char lds[2 * QBUF];
  const int tid = threadIdx.x;
  const int nwg = gridDim.x;
  const int g = blockIdx.x;
  const int swz = (g & 7) * (nwg >> 3) + (g >> 3);   // XCD-chunked, nwg%8==0
  const int bn = swz & ((1 << lgn) - 1);             // N fastest: A-panel L2 reuse
  const int bm = swz >> lgn;
  const int lane = tid & 63;
  const int wid = tid >> 6;
  const int wr = wid >> 2;          // 0..1 : 128-row half
  const int wc = wid & 3;           // 0..3 : 64-col slab
  const int fr = lane & 15;
  const int kg = lane >> 4;         // 0..3

  // staging: 8 granule-sets/thread/K-tile; gid=j*512+tid; j<4 -> A, else B.
  // LDS dest = gid*16 (linear); source granule pre-swizzled gr^(row&7).
  int srcOff[8];
  #pragma unroll
  for (int j = 0; j < 8; j++) {
    int gid = j * 512 + tid;
    int row = (gid >> 3) & 255;
    int gr = gid & 7;
    int gsw = gr ^ (row & 7);
    srcOff[j] = ((j < 4 ? bm : bn) * 256 + row) * K + gsw * 8;
  }
  const int ldsBase = tid * 16;     // + j*8192

  const int x7 = fr & 7;                       // swizzle key (row&7 == fr&7)
  const int aBase = (wr*128 + fr) * 128;       // + m*2048
  const int bBase = 32768 + (wc*64 + fr) * 128;// + n*2048

  f32x4 acc[8][4];
  #pragma unroll
  for (int m = 0; m < 8; m++)
    #pragma unroll
    for (int n = 0; n < 4; n++)
      #pragma unroll
      for (int r = 0; r < 4; r++) acc[m][n][r] = 0.f;

  auto STAGEH = [&](int t2, int sbuf, int j0) {   // 2 wave-loads = 16 KB
    char* dst = (char*)lds + sbuf * QBUF;
    const size_t kof = (size_t)t2 * 64;
    #pragma unroll
    for (int j = j0; j < j0 + 2; j++) {
      const f16* src = (j < 4 ? A : BT) + srcOff[j] + kof;
      __builtin_amdgcn_global_load_lds((gas1)src, (las3)(dst + ldsBase + j*8192), 16, 0, 0);
    }
  };
  auto READF = [&](f16x8* av, f16x8* bv, const char* rb, int s) {
    const int ko = ((s*4 + kg) ^ x7) << 4;
    #pragma unroll
    for (int m = 0; m < 8; m++) av[m] = *(const f16x8*)(rb + aBase + m*2048 + ko);
    #pragma unroll
    for (int n = 0; n < 4; n++) bv[n] = *(const f16x8*)(rb + bBase + n*2048 + ko);
  };

  f16x8 av[8], bv[4];
  const int NT = K >> 6;
  STAGEH(0, 0, 0); STAGEH(0, 0, 2); STAGEH(0, 0, 4); STAGEH(0, 0, 6);
  asm volatile("s_waitcnt vmcnt(0)" ::: "memory");
  asm volatile("s_barrier" ::: "memory");

  for (int t = 0; t < NT; t++) {
    const char* rb = (const char*)lds + (t & 1) * QBUF;
    const int nb = (t + 1) & 1;
    const bool stg = (t + 1) < NT;

    if (stg) { STAGEH(t + 1, nb, 0); STAGEH(t + 1, nb, 2); }   // A-tile
    READF(av, bv, rb, 0);
    __builtin_amdgcn_s_setprio(1);
    #pragma unroll
    for (int m = 0; m < 8; m++)
      #pragma unroll
      for (int n = 0; n < 4; n++)
        acc[m][n] = __builtin_amdgcn_mfma_f32_16x16x32_f16(bv[n], av[m], acc[m][n], 0, 0, 0);
    __builtin_amdgcn_s_setprio(0);
    if (stg) { STAGEH(t + 1, nb, 4); STAGEH(t + 1, nb, 6); }   // B-tile
    READF(av, bv, rb, 1);
    __builtin_amdgcn_s_setprio(1);
    #pragma unroll
    for (int m = 0; m < 8; m++)
      #pragma unroll
      for (int n = 0; n < 4; n++)
        acc[m][n] = __builtin_amdgcn_mfma_f32_16x16x32_f16(bv[n], av[m], acc[m][n], 0, 0, 0);
    __builtin_amdgcn_s_setprio(0);
    if (stg) asm volatile("s_waitcnt vmcnt(0)" ::: "memory");
    asm volatile("s_barrier" ::: "memory");   // tile t+1 resident; buf[t&1] reads retired
  }

  // swapped-operand C layout: C[bm*256 + wr*128 + m*16 + fr]
  //                            [bn*256 + wc*64 + n*16 + kg*4 + r]
  const int crow = bm*256 + wr*128 + fr;    // + m*16
  const int ccol = bn*256 + wc*64 + kg*4;   // + n*16, r contiguous
  if constexpr (MODE == 2) {
    #pragma unroll
    for (int n = 0; n < 4; n++) {
      float4 bb = *(const float4*)(bias + ccol + n*16);
      #pragma unroll
      for (int m = 0; m < 8; m++) {
        float4 v;
        v.x = acc[m][n][0] + bb.x; v.y = acc[m][n][1] + bb.y;
        v.z = acc[m][n][2] + bb.z; v.w = acc[m][n][3] + bb.w;
        *(float4*)(Cf + (size_t)(crow + m*16) * N + ccol + n*16) = v;
      }
    }
  } else {
    #pragma unroll
    for (int m = 0; m < 8; m++)
      #pragma unroll
      for (int n = 0; n < 4; n++) {
        f16x4 o;
        o[0] = (f16)acc[m][n][0]; o[1] = (f16)acc[m][n][1];
        o[2] = (f16)acc[m][n][2]; o[3] = (f16)acc[m][n][3];
        *(f16x4*)(C1 + (size_t)(crow + m*16) * N + ccol + n*16) = o;
      }
  }
  if constexpr (MODE == 1) {
    // column-stat partials over this block's 256 rows.
    float s[4][4], q[4][4];
    #pragma unroll
    for (int n = 0; n < 4; n++)
      #pragma unroll
      for (int r = 0; r < 4; r++) {
        float ss = 0.f, qq = 0.f;
        #pragma unroll
        for (int m = 0; m < 8; m++) { float v = acc[m][n][r]; ss += v; qq = fmaf(v, v, qq); }
        s[n][r] = ss; q[n][r] = qq;
      }
    #pragma unroll
    for (int n = 0; n < 4; n++)
      #pragma unroll
      for (int r = 0; r < 4; r++) {
        s[n][r] += __shfl_xor(s[n][r], 1); s[n][r] += __shfl_xor(s[n][r], 2);
        s[n][r] += __shfl_xor(s[n][r], 4); s[n][r] += __shfl_xor(s[n][r], 8);
        q[n][r] += __shfl_xor(q[n][r], 1); q[n][r] += __shfl_xor(q[n][r], 2);
        q[n][r] += __shfl_xor(q[n][r], 4); q[n][r] += __shfl_xor(q[n][r], 8);
      }
    float* wred = (float*)lds;   // [sum: [wr][256]] [sq: [wr][256]] = 4 KB
    __syncthreads();
    if (fr == 0) {
      #pragma unroll
      for (int n = 0; n < 4; n++)
        #pragma unroll
        for (int r = 0; r < 4; r++) {
          int c = wc*64 + n*16 + kg*4 + r;
          wred[wr*256 + c]       = s[n][r];
          wred[512 + wr*256 + c] = q[n][r];
        }
    }
    __syncthreads();
    if (tid < 256) {
      psum[(size_t)bm * N + bn*256 + tid] = wred[tid]       + wred[256 + tid];
      psq [(size_t)bm * N + bn*256 + tid] = wred[512 + tid] + wred[768 + tid];
    }
  }
}

// ---------------- in-place mix on [M][512] (xg -> mix(xg)) ----------------
__global__ __launch_bounds__(256)
void k_mixip(f16* __restrict__ t, const float* __restrict__ Aadj) {
  __shared__ float A[441];
  int b = blockIdx.x, tid = threadIdx.x;
  for (int i = tid; i < 441; i += 256) A[i] = Aadj[i];
  __syncthreads();
  int c0 = tid * 2;
  size_t base = (size_t)b * NN * 512 + c0;
  float vx[21], vy[21];
  #pragma unroll
  for (int j = 0; j < 21; j++) {
    f16x2 v = *(const f16x2*)(t + base + (size_t)j * 512);
    vx[j] = (float)v[0]; vy[j] = (float)v[1];
  }
  #pragma unroll
  for (int i = 0; i < 21; i++) {
    float a0 = 0.f, a1 = 0.f;
    #pragma unroll
    for (int j = 0; j < 21; j++) { float w = A[i*21+j]; a0 = fmaf(w, vx[j], a0); a1 = fmaf(w, vy[j], a1); }
    f16x2 o; o[0] = (f16)a0; o[1] = (f16)a1;
    *(f16x2*)(t + base + (size_t)i * 512) = o;
  }
}

// ------- per-graph 21x21 mix, in-place + per-graph BN stats -------
__global__ __launch_bounds__(256)
void k_mix(f16* __restrict__ t, const float* __restrict__ Aadj,
           float* __restrict__ psum, float* __restrict__ psq, int C) {
  __shared__ float A[441];
  int b = blockIdx.x, tid = threadIdx.x;
  for (int i = tid; i < 441; i += 256) A[i] = Aadj[i];
  __syncthreads();
  int c0 = (blockIdx.y * 256 + tid) * 2;
  size_t base = (size_t)b * NN * C + c0;
  float vx[21], vy[21];
  #pragma unroll
  for (int j = 0; j < 21; j++) {
    f16x2 v = *(const f16x2*)(t + base + (size_t)j * C);
    vx[j] = (float)v[0]; vy[j] = (float)v[1];
  }
  float s0 = 0.f, s1 = 0.f, q0 = 0.f, q1 = 0.f;
  #pragma unroll
  for (int i = 0; i < 21; i++) {
    float a0 = 0.f, a1 = 0.f;
    #pragma unroll
    for (int j = 0; j < 21; j++) {
      float w = A[i*21 + j];
      a0 = fmaf(w, vx[j], a0);
      a1 = fmaf(w, vy[j], a1);
    }
    f16x2 o; o[0] = (f16)a0; o[1] = (f16)a1;
    *(f16x2*)(t + base + (size_t)i * C) = o;
    s0 += a0; s1 += a1;
    q0 = fmaf(a0, a0, q0); q1 = fmaf(a1, a1, q1);
  }
  float2 sv; sv.x = s0; sv.y = s1;
  float2 qv; qv.x = q0; qv.y = q1;
  *(float2*)(psum + (size_t)b * C + c0) = sv;
  *(float2*)(psq  + (size_t)b * C + c0) = qv;
}

// ---------------- reduce partials -> groups (deterministic) --------------
__global__ void k_reduce(const float* __restrict__ ps, const float* __restrict__ pq,
                         float* __restrict__ rs, float* __restrict__ rq,
                         int C, int per) {
  int c = blockIdx.x * 256 + threadIdx.x;
  int py = blockIdx.y;
  float s = 0.f, q = 0.f;
  for (int p = py*per; p < py*per + per; p++) {
    s += ps[(size_t)p*C + c];
    q += pq[(size_t)p*C + c];
  }
  rs[(size_t)py*C + c] = s;
  rq[(size_t)py*C + c] = q;
}

__global__ void k_bnparams(const float* __restrict__ psum, const float* __restrict__ psq,
                           const float* __restrict__ gamma, const float* __restrict__ beta,
                           const float* __restrict__ resbias,
                           float* __restrict__ scale, float* __restrict__ shift,
                           int C, int npart) {
  int c = blockIdx.x * 256 + threadIdx.x;
  float s = 0.f, q = 0.f;
  for (int p = 0; p < npart; p++) { s += psum[(size_t)p*C + c]; q += psq[(size_t)p*C + c]; }
  const float Minv = 1.f / (float)MROWS;
  float mean = s * Minv;
  float var = q * Minv - mean * mean;
  float sc = gamma[c] * rsqrtf(var + 1e-5f);
  float sh = beta[c] - mean * sc;
  if (resbias) sh += resbias[c];
  scale[c] = sc; shift[c] = sh;
}

// ---------------- finalize: dst = relu(g*scale + shift + res) ----------------
__global__ void k_finalize(const f16* __restrict__ g, const f16* res,
                           f16* dst, const float* __restrict__ scale,
                           const float* __restrict__ shift, int cmask) {
  size_t i8 = (size_t)blockIdx.x * 256 + threadIdx.x;
  size_t base = i8 * 8;
  int c = (int)(base & (size_t)cmask);
  f16x8 gv = *(const f16x8*)(g + base);
  f16x8 rv = *(const f16x8*)(res + base);
  f16x8 o;
  #pragma unroll
  for (int j = 0; j < 8; j++) {
    float v = (float)gv[j] * scale[c + j] + shift[c + j] + (float)rv[j];
    o[j] = (f16)fmaxf(v, 0.f);
  }
  *(f16x8*)(dst + base) = o;
}

// ---------------- fused finish + mix: hmix = mix(relu(t*sc+sh+res)) ---------
__global__ __launch_bounds__(256)
void k_finmix(const f16* t, const f16* res, f16* hout, f16* hmix,
              const float* __restrict__ scale, const float* __restrict__ shift,
              const float* __restrict__ Aadj, int C) {
  __shared__ float A[441];
  int b = blockIdx.x, tid = threadIdx.x;
  for (int i = tid; i < 441; i += 256) A[i] = Aadj[i];
  __syncthreads();
  int c0 = (blockIdx.y * 256 + tid) * 2;
  float scx = scale[c0], scy = scale[c0+1];
  float shx = shift[c0], shy = shift[c0+1];
  size_t base = (size_t)b * NN * C + c0;
  float hx[21], hy[21];
  #pragma unroll
  for (int j = 0; j < 21; j++) {
    f16x2 tv = *(const f16x2*)(t + base + (size_t)j*C);
    f16x2 rv = *(const f16x2*)(res + base + (size_t)j*C);
    hx[j] = fmaxf((float)tv[0]*scx + shx + (float)rv[0], 0.f);
    hy[j] = fmaxf((float)tv[1]*scy + shy + (float)rv[1], 0.f);
    if (hout) {
      f16x2 o; o[0] = (f16)hx[j]; o[1] = (f16)hy[j];
      *(f16x2*)(hout + base + (size_t)j*C) = o;
    }
  }
  #pragma unroll
  for (int i = 0; i < 21; i++) {
    float a0 = 0.f, a1 = 0.f;
    #pragma unroll
    for (int j = 0; j < 21; j++) { float w = A[i*21+j]; a0 = fmaf(w, hx[j], a0); a1 = fmaf(w, hy[j], a1); }
    f16x2 o; o[0] = (f16)a0; o[1] = (f16)a1;
    *(f16x2*)(hmix + base + (size_t)i*C) = o;
  }
}

// ---------------- pool (mean over 21) + BN affine -> f16 ----------------
__global__ void k_pool(const f16* __restrict__ g3, const float* __restrict__ scale,
                       const float* __restrict__ shift, f16* __restrict__ pooled) {
  int b = blockIdx.x, t = threadIdx.x;
  for (int c = t; c < 512; c += 256) {
    float s = 0.f;
    #pragma unroll
    for (int n = 0; n < NN; n++) s += (float)g3[((size_t)b*NN + n)*512 + c];
    pooled[(size_t)b*512 + c] = (f16)((s * (1.f/21.f)) * scale[c] + shift[c]);
  }
}

extern "C" void kernel_launch(void* const* d_in, const int* in_sizes, int n_in,
                              void* d_out, int out_size, void* d_ws, size_t ws_size,
                              hipStream_t stream) {
  const float* x     = (const float*)d_in[0];
  const float* nv1   = (const float*)d_in[2];
  const float* nv2   = (const float*)d_in[3];
  const float* se_w1 = (const float*)d_in[4];
  const float* se_w2 = (const float*)d_in[5];
  const float* W1    = (const float*)d_in[6];
  const float* W2    = (const float*)d_in[8];
  const float* W3    = (const float*)d_in[10];
  const float* bn1g  = (const float*)d_in[12];
  const float* bn1b  = (const float*)d_in[13];
  const float* bn2g  = (const float*)d_in[14];
  const float* bn2b  = (const float*)d_in[15];
  const float* bn3g  = (const float*)d_in[16];
  const float* bn3b  = (const float*)d_in[17];
  const float* rs1w  = (const float*)d_in[18];
  const float* rs1b  = (const float*)d_in[19];
  const float* fcw   = (const float*)d_in[20];
  const float* fcb   = (const float*)d_in[21];
  float* out = (float*)d_out;

  char* ws = (char*)d_ws;
  size_t off = 0;
  auto alloc = [&](size_t bytes) -> char* {
    char* p = ws + off;
    off = (off + bytes + 255) & ~(size_t)255;
    return p;
  };

  // total ws footprint ~470 MB (known-good <=484; 738 aborted in round 7)
  float* A_adj = (float*)alloc(441 * 4);
  f16* W1T  = (f16*)alloc((size_t)1024 * 512 * 2);
  f16* RS1T = (f16*)alloc((size_t)1024 * 512 * 2);
  f16* W2T  = (f16*)alloc((size_t)1024 * 1024 * 2);
  f16* W3T  = (f16*)alloc((size_t)512 * 1024 * 2);
  f16* FCWT = (f16*)alloc((size_t)1024 * 512 * 2);
  float* psum = (float*)alloc((size_t)NB * 1024 * 4);    // 16MB; aliases xm
  float* psq  = (float*)alloc((size_t)NB * 1024 * 4);    // 16MB; aliases yv
  float* y1   = (float*)alloc((size_t)NB * 128 * 4);
  float* rsum = (float*)alloc((size_t)32 * 1024 * 4);
  float* rsq  = (float*)alloc((size_t)32 * 1024 * 4);
  float* sc1 = (float*)alloc(1024 * 4);
  float* sh1 = (float*)alloc(1024 * 4);
  float* sc2 = (float*)alloc(1024 * 4);
  float* sh2 = (float*)alloc(1024 * 4);
  float* sc3 = (float*)alloc(1024 * 4);
  float* sh3 = (float*)alloc(1024 * 4);
  f16* pooled = (f16*)alloc((size_t)NB * 512 * 2);
  f16* G = (f16*)alloc((size_t)MROWS * 512 * 2);     // xg -> xgm -> T3
  f16* R = (f16*)alloc((size_t)MROWS * 1024 * 2);    // R1 -> h1
  f16* T = (f16*)alloc((size_t)MROWS * 1024 * 2);    // T1 -> T2/t2m -> h2m
  float* xm = psum;   // dead before psum first written
  float* yv = psq;    // dead after k_gate, before psq first written
  (void)ws_size; (void)in_sizes; (void)n_in; (void)out_size;

  // adjacency + batched weight transposes (1 launch)
  k_adj<<<1, 512, 0, stream>>>(nv1, nv2, A_adj);
  k_transpose_all<<<3072, dim3(32, 8), 0, stream>>>(W1, rs1w, W2, W3, fcw,
                                                    W1T, RS1T, W2T, W3T, FCWT);

  // SE path + gate (r10 forms)
  k_mean<<<NB, 256, 0, stream>>>(x, xm);
  k_se1<<<NB, 128, 0, stream>>>(xm, se_w1, y1);
  k_se2<<<NB, 512, 0, stream>>>(y1, se_w2, yv);
  k_gate<<<21504, 256, 0, stream>>>(x, yv, G);

  // layer 1: R1 = xg@rs1w; xgm = mix(xg) in place; T1 = xgm@W1 (+fused stats)
  // M-tiles = 86016/256 = 336; N=1024 -> 4 N-tiles (lgn=2) -> 1344 blocks
  k_gemm256<0><<<1344, 512, 0, stream>>>(G, RS1T, R, nullptr, nullptr, nullptr, nullptr, 1024, 512, 2);
  k_mixip<<<NB, 256, 0, stream>>>(G, A_adj);
  k_gemm256<1><<<1344, 512, 0, stream>>>(G, W1T, T, nullptr, nullptr, psum, psq, 1024, 512, 2);
  k_reduce<<<dim3(4, 24), 256, 0, stream>>>(psum, psq, rsum, rsq, 1024, 14);   // 24*14 = 336
  k_bnparams<<<4, 256, 0, stream>>>(rsum, rsq, bn1g, bn1b, rs1b, sc1, sh1, 1024, 24);
  k_finalize<<<43008, 256, 0, stream>>>(T, R, R, sc1, sh1, 1023);     // h1 -> R

  // layer 2: T2 = h1@W2; mix+stats in place; h2m = mix(relu(BN(t2m)+h1)) -> T
  k_gemm256<0><<<1344, 512, 0, stream>>>(R, W2T, T, nullptr, nullptr, nullptr, nullptr, 1024, 1024, 2);
  k_mix<<<dim3(NB, 2), 256, 0, stream>>>(T, A_adj, psum, psq, 1024);
  k_reduce<<<dim3(4, 32), 256, 0, stream>>>(psum, psq, rsum, rsq, 1024, 128);
  k_bnparams<<<4, 256, 0, stream>>>(rsum, rsq, bn2g, bn2b, nullptr, sc2, sh2, 1024, 32);
  k_finmix<<<dim3(NB, 2), 256, 0, stream>>>(T, R, nullptr, T, sc2, sh2, A_adj, 1024);

  // layer 3: T3 = h2m@W3 (+fused stats) -> G ; N=512 -> 2 N-tiles (lgn=1)
  k_gemm256<1><<<672, 512, 0, stream>>>(T, W3T, G, nullptr, nullptr, psum, psq, 512, 1024, 1);
  k_reduce<<<dim3(2, 24), 256, 0, stream>>>(psum, psq, rsum, rsq, 512, 14);
  k_bnparams<<<2, 256, 0, stream>>>(rsum, rsq, bn3g, bn3b, nullptr, sc3, sh3, 512, 24);

  // pool + fc : M=4096 -> 16 m-tiles x 4 n-tiles = 64 blocks
  k_pool<<<NB, 256, 0, stream>>>(G, sc3, sh3, pooled);
  k_gemm256<2><<<64, 512, 0, stream>>>(pooled, FCWT, nullptr, fcb, out, nullptr, nullptr, 1024, 512, 2);
}